// Round 7
// baseline (216.223 us; speedup 1.0000x reference)
//
#include <hip/hip_runtime.h>
#include <hip/hip_bf16.h>

// Problem constants (fixed by reference)
#define B_   2
#define S_   2048
#define HID_ 1024
#define NH_  16
#define HD_  64

typedef __hip_bfloat16 bf16;
typedef __attribute__((ext_vector_type(8))) short s8v;   // 8 bf16 = 4 VGPR (MFMA A/B frag)
typedef __attribute__((ext_vector_type(4))) float f4v;   // MFMA C/D frag

// Q pre-scale: 0.125 (1/sqrt(64)) * log2(e) -> exp2(score) == exp(q.k/8) exactly
#define QSCALE 0.18033688011112042f

__device__ __forceinline__ unsigned short f2b_rne(float x) {
    unsigned int u = __float_as_uint(x);
    u += 0x7fffu + ((u >> 16) & 1u);
    return (unsigned short)(u >> 16);
}

__device__ __forceinline__ float b2f(unsigned short u) {
    return __uint_as_float(((unsigned int)u) << 16);
}

__device__ __forceinline__ void gload_lds16(const void* g, void* l) {
    __builtin_amdgcn_global_load_lds(
        (const __attribute__((address_space(1))) void*)g,
        (__attribute__((address_space(3))) void*)l, 16, 0, 0);
}

// ---------------------------------------------------------------------------
// Prep: z=0..3 -> transpose W_z fp32 [k][n] -> bf16 [n][k]; z=4..7 -> convert
// a quarter of X fp32 -> bf16 (layout-preserving). grid (16,16,8), 256 thr.
// ---------------------------------------------------------------------------
__global__ __launch_bounds__(256) void prep_kernel(
    const float* __restrict__ X,
    const float* __restrict__ W0, const float* __restrict__ W1,
    const float* __restrict__ W2, const float* __restrict__ W3,
    unsigned short* __restrict__ Xb,
    unsigned short* __restrict__ T0, unsigned short* __restrict__ T1,
    unsigned short* __restrict__ T2, unsigned short* __restrict__ T3)
{
    const int z = blockIdx.z;
    const int t = threadIdx.x;

    if (z >= 4) {
        // convert quarter (z-4): 256 blocks x 256 thr x 16 elems
        const size_t base = ((size_t)(z - 4) * 256 + blockIdx.y * 16 + blockIdx.x) * 4096;
        #pragma unroll
        for (int p = 0; p < 4; ++p) {
            const size_t i = base + p * 1024 + t * 4;
            const float4 f = *reinterpret_cast<const float4*>(X + i);
            ushort4 u;
            u.x = f2b_rne(f.x); u.y = f2b_rne(f.y); u.z = f2b_rne(f.z); u.w = f2b_rne(f.w);
            *reinterpret_cast<ushort4*>(Xb + i) = u;
        }
        return;
    }

    const float* __restrict__ W = (z == 0) ? W0 : (z == 1) ? W1 : (z == 2) ? W2 : W3;
    unsigned short* __restrict__ T = (z == 0) ? T0 : (z == 1) ? T1 : (z == 2) ? T2 : T3;

    __shared__ float Tl[64][65];
    const int n0 = blockIdx.x * 64, k0 = blockIdx.y * 64;
    const int rr = t >> 4, c4 = (t & 15) * 4;

    #pragma unroll
    for (int i = 0; i < 4; ++i) {
        const int kr = i * 16 + rr;
        const float4 f = *reinterpret_cast<const float4*>(W + (size_t)(k0 + kr) * HID_ + n0 + c4);
        Tl[c4 + 0][kr] = f.x; Tl[c4 + 1][kr] = f.y;
        Tl[c4 + 2][kr] = f.z; Tl[c4 + 3][kr] = f.w;
    }
    __syncthreads();
    #pragma unroll
    for (int i = 0; i < 4; ++i) {
        const int nr = i * 16 + rr;
        ushort4 u;
        u.x = f2b_rne(Tl[nr][c4 + 0]); u.y = f2b_rne(Tl[nr][c4 + 1]);
        u.z = f2b_rne(Tl[nr][c4 + 2]); u.w = f2b_rne(Tl[nr][c4 + 3]);
        *reinterpret_cast<ushort4*>(T + (size_t)(n0 + nr) * HID_ + k0 + c4) = u;
    }
}

// ---------------------------------------------------------------------------
// Shared MFMA mainloop: 128x128 tile, BK=64, 4 waves 2x2, global_load_lds
// staging with XOR chunk swizzle. A [m][k], Bt [n][k], both bf16 k-major.
// ---------------------------------------------------------------------------
__device__ __forceinline__ void mfma_mainloop(
    const unsigned short* __restrict__ Ag, const unsigned short* __restrict__ Bg,
    unsigned short* As, unsigned short* Bs,
    int m0, int n0, int t, f4v acc[4][4])
{
    const int w = t >> 6, lane = t & 63;
    const int l15 = lane & 15, qd = lane >> 4;
    const int wm = (w & 1) * 64, wn = (w >> 1) * 64;
    const int srow = w * 8 + (lane >> 3);
    const int lc8  = (((lane & 7) ^ (lane >> 3)) * 8);

    for (int k0 = 0; k0 < HID_; k0 += 64) {
        __syncthreads();
        #pragma unroll
        for (int it = 0; it < 4; ++it) {
            const int row = it * 32 + srow;
            const int sb = (it * 256 + w * 64) * 8;
            gload_lds16(Ag + (size_t)(m0 + row) * HID_ + k0 + lc8, As + sb);
            gload_lds16(Bg + (size_t)(n0 + row) * HID_ + k0 + lc8, Bs + sb);
        }
        __syncthreads();
        #pragma unroll
        for (int kc = 0; kc < 2; ++kc) {
            const int p = ((kc * 4 + qd) ^ (l15 & 7)) * 8;
            s8v af[4], bf[4];
            #pragma unroll
            for (int mt = 0; mt < 4; ++mt)
                af[mt] = *reinterpret_cast<const s8v*>(As + (wm + mt * 16 + l15) * 64 + p);
            #pragma unroll
            for (int nt = 0; nt < 4; ++nt)
                bf[nt] = *reinterpret_cast<const s8v*>(Bs + (wn + nt * 16 + l15) * 64 + p);
            #pragma unroll
            for (int mt = 0; mt < 4; ++mt)
                #pragma unroll
                for (int nt = 0; nt < 4; ++nt)
                    acc[mt][nt] = __builtin_amdgcn_mfma_f32_16x16x32_bf16(
                        af[mt], bf[nt], acc[mt][nt], 0, 0, 0);
        }
    }
}

// ---------------------------------------------------------------------------
// Kernel: QKV projection GEMM + bias + axial RoPE epilogue.
// Q is additionally pre-scaled by QSCALE (softmax exp2 fold).
// ---------------------------------------------------------------------------
__global__ __launch_bounds__(256) void gemm_qkv_kernel(
    const unsigned short* __restrict__ Xb,
    const unsigned short* __restrict__ Wqt, const unsigned short* __restrict__ Wkt,
    const unsigned short* __restrict__ Wvt,
    const float* __restrict__ bq, const float* __restrict__ bk, const float* __restrict__ bv,
    unsigned short* __restrict__ Qb, unsigned short* __restrict__ Kb,
    unsigned short* __restrict__ Vt)
{
    const int z = blockIdx.z;
    const unsigned short* __restrict__ Bt = (z == 0) ? Wqt : (z == 1) ? Wkt : Wvt;
    const float* __restrict__ bias = (z == 0) ? bq : (z == 1) ? bk : bv;

    const int n0 = blockIdx.x * 128, m0 = blockIdx.y * 128;
    const int t = threadIdx.x;
    const int w = t >> 6, lane = t & 63;
    const int l15 = lane & 15, qd = lane >> 4;
    const int wm = (w & 1) * 64, wn = (w >> 1) * 64;

    __shared__ unsigned short As[128 * 64];
    __shared__ unsigned short Bs[128 * 64];

    f4v acc[4][4];
    #pragma unroll
    for (int mt = 0; mt < 4; ++mt)
        #pragma unroll
        for (int nt = 0; nt < 4; ++nt) acc[mt][nt] = (f4v){0.f, 0.f, 0.f, 0.f};

    mfma_mainloop(Xb, Bt, As, Bs, m0, n0, t, acc);

    const float osc = (z == 0) ? QSCALE : 1.f;

    #pragma unroll
    for (int nt = 0; nt < 4; ++nt) {
        const int col = n0 + wn + nt * 16 + l15;   // 0..1023
        const int h = col >> 6, d = col & 63;
        const float bsc = bias[col];
        const int seg = d / 20;
        const int ds  = d - seg * 20;
        const float om   = __expf(-0.9210340372f * (float)(ds % 10));
        const float sign = (d & 1) ? 1.f : -1.f;

        #pragma unroll
        for (int mt = 0; mt < 4; ++mt) {
            const int mbase = m0 + wm + mt * 16 + qd * 4;
            const int b = mbase >> 11;
            const int sbase = mbase & 2047;
            if (z == 2) {
                ushort4 u;
                unsigned short* up = (unsigned short*)&u;
                #pragma unroll
                for (int r = 0; r < 4; ++r) up[r] = f2b_rne(acc[mt][nt][r] + bsc);
                *reinterpret_cast<ushort4*>(
                    Vt + ((size_t)(b * NH_ + h) * HD_ + d) * S_ + sbase) = u;
            } else {
                unsigned short* __restrict__ dst = (z == 0 ? Qb : Kb)
                    + ((size_t)(b * NH_ + h) * S_ + sbase) * HD_ + d;
                #pragma unroll
                for (int r = 0; r < 4; ++r) {
                    const int s = sbase + r;
                    float v = acc[mt][nt][r] + bsc;
                    const float xp = __shfl_xor(v, 1);
                    if (d < 60) {
                        const int rem = s & 255;
                        const float pos = (float)(seg == 0 ? (s >> 8)
                                               : (seg == 1 ? (rem >> 4) : (rem & 15)));
                        const float a = pos * om;
                        float sn, cs;
                        __sincosf(a, &sn, &cs);
                        v = v * cs + sign * xp * sn;
                    }
                    dst[(size_t)r * HD_] = f2b_rne(v * osc);
                }
            }
        }
    }
}

// ---------------------------------------------------------------------------
// Kernel: output projection GEMM + bias -> fp32 out. grid (8, 32).
// ---------------------------------------------------------------------------
__global__ __launch_bounds__(256) void gemm_out_kernel(
    const unsigned short* __restrict__ Cb, const unsigned short* __restrict__ Wot,
    const float* __restrict__ bo, float* __restrict__ out)
{
    const int n0 = blockIdx.x * 128, m0 = blockIdx.y * 128;
    const int t = threadIdx.x;
    const int w = t >> 6, lane = t & 63;
    const int l15 = lane & 15, qd = lane >> 4;
    const int wm = (w & 1) * 64, wn = (w >> 1) * 64;

    __shared__ unsigned short As[128 * 64];
    __shared__ unsigned short Bs[128 * 64];

    f4v acc[4][4];
    #pragma unroll
    for (int mt = 0; mt < 4; ++mt)
        #pragma unroll
        for (int nt = 0; nt < 4; ++nt) acc[mt][nt] = (f4v){0.f, 0.f, 0.f, 0.f};

    mfma_mainloop(Cb, Wot, As, Bs, m0, n0, t, acc);

    #pragma unroll
    for (int nt = 0; nt < 4; ++nt) {
        const int col = n0 + wn + nt * 16 + l15;
        const float bsc = bo[col];
        #pragma unroll
        for (int mt = 0; mt < 4; ++mt) {
            const int mbase = m0 + wm + mt * 16 + qd * 4;
            #pragma unroll
            for (int r = 0; r < 4; ++r)
                out[(size_t)(mbase + r) * HID_ + col] = acc[mt][nt][r] + bsc;
        }
    }
}

// ---------------------------------------------------------------------------
// Kernel: MFMA flash attention v4 — kv-split-2 partials.
// grid (16 q-tiles, 32 bh, 2 kv-halves). Block = 4 waves, 128 q-rows,
// kv range = [half*1024, half*1024+1024), 8 tiles of 128 kv.
// Per tile, kv processed in two 64-halves reusing one Ps buffer (per-wave
// private, program order) -> LDS 50 KB -> 3 blocks/CU.
// Emits UNNORMALIZED O (bf16) and L (f32) partials; combine_kernel divides.
// ---------------------------------------------------------------------------
__global__ __launch_bounds__(256, 3) void attn_kernel(
    const bf16* __restrict__ Qb, const bf16* __restrict__ Kb,
    const bf16* __restrict__ Vt,
    unsigned short* __restrict__ O0, unsigned short* __restrict__ O1,
    float* __restrict__ Lp)
{
    const int q0 = blockIdx.x * 128;
    const int bh = blockIdx.y;
    const int half = blockIdx.z;
    const int b  = bh >> 4, h = bh & 15;
    const int t  = threadIdx.x;
    const int w  = t >> 6;
    const int lane = t & 63;
    const int l15 = lane & 15, qd = lane >> 4;

    __shared__ unsigned short Ks[128 * 64];   // [kv][d], chunk-swizzled by kv&7
    __shared__ unsigned short Vs[64 * 128];   // [d][kv], chunk-swizzled by d&15
    __shared__ unsigned short Ps[128 * 72];   // [q][kv 64-half], per-wave rows

    // Q B-frags (pre-scaled by QSCALE in the projection epilogue)
    s8v bq[2][2];
    #pragma unroll
    for (int g = 0; g < 2; ++g) {
        const bf16* Qrow = Qb + ((size_t)bh * S_ + q0 + w * 32 + g * 16 + l15) * HD_ + qd * 8;
        bq[g][0] = *reinterpret_cast<const s8v*>(Qrow);
        bq[g][1] = *reinterpret_cast<const s8v*>(Qrow + 32);
    }

    f4v oacc[2][4];
    float lacc[2] = {0.f, 0.f};
    #pragma unroll
    for (int g = 0; g < 2; ++g)
        #pragma unroll
        for (int dt = 0; dt < 4; ++dt) oacc[g][dt] = (f4v){0.f, 0.f, 0.f, 0.f};

    const bf16* __restrict__ Kg = Kb + (size_t)bh * S_ * HD_;
    const bf16* __restrict__ Vg = Vt + (size_t)bh * HD_ * S_;

    const int krow = lane >> 3;                     // 0..7
    const int ksw  = ((lane & 7) ^ krow) * 8;       // K source chunk swizzle
    const int vrow = lane >> 4;                     // 0..3

    const int kbeg = half * 1024;
    for (int k0 = kbeg; k0 < kbeg + 1024; k0 += 128) {
        __syncthreads();   // all waves done reading Ks/Vs from previous tile
        #pragma unroll
        for (int it = 0; it < 4; ++it) {
            gload_lds16(Kg + (size_t)(k0 + w * 32 + it * 8 + krow) * HD_ + ksw,
                        Ks + (w * 32 + it * 8) * 64);
        }
        #pragma unroll
        for (int it = 0; it < 4; ++it) {
            const int r = w * 16 + it * 4 + vrow;   // d row
            const int sv = ((lane & 15) ^ (r & 15)) * 8;
            gload_lds16(Vg + (size_t)r * S_ + k0 + sv,
                        Vs + (w * 16 + it * 4) * 128);
        }
        __syncthreads();

        #pragma unroll
        for (int hi = 0; hi < 2; ++hi) {
            // ---- scores (transposed) for kv rows [hi*64, hi*64+64)
            #pragma unroll
            for (int nth = 0; nth < 4; ++nth) {
                const unsigned short* kr = Ks + (hi * 64 + nth * 16 + l15) * 64;
                const s8v ak0 = *reinterpret_cast<const s8v*>(kr + ((qd ^ (l15 & 7)) * 8));
                const s8v ak1 = *reinterpret_cast<const s8v*>(kr + (((qd + 4) ^ (l15 & 7)) * 8));
                #pragma unroll
                for (int g = 0; g < 2; ++g) {
                    f4v zz = (f4v){0.f, 0.f, 0.f, 0.f};
                    zz = __builtin_amdgcn_mfma_f32_16x16x32_bf16(ak0, bq[g][0], zz, 0, 0, 0);
                    zz = __builtin_amdgcn_mfma_f32_16x16x32_bf16(ak1, bq[g][1], zz, 0, 0, 0);
                    const float p0 = __builtin_amdgcn_exp2f(zz[0]);
                    const float p1 = __builtin_amdgcn_exp2f(zz[1]);
                    const float p2 = __builtin_amdgcn_exp2f(zz[2]);
                    const float p3 = __builtin_amdgcn_exp2f(zz[3]);
                    const unsigned int u01 = __builtin_amdgcn_perm(
                        __float_as_uint(p1), __float_as_uint(p0), 0x07060302u);
                    const unsigned int u23 = __builtin_amdgcn_perm(
                        __float_as_uint(p3), __float_as_uint(p2), 0x07060302u);
                    // l from the SAME truncated values (consistency with PV)
                    const float t0 = __uint_as_float(u01 << 16);
                    const float t1 = __uint_as_float(u01 & 0xffff0000u);
                    const float t2 = __uint_as_float(u23 << 16);
                    const float t3 = __uint_as_float(u23 & 0xffff0000u);
                    lacc[g] += (t0 + t1) + (t2 + t3);
                    *reinterpret_cast<uint2*>(
                        Ps + (w * 32 + g * 16 + l15) * 72 + nth * 16 + qd * 4) =
                        make_uint2(u01, u23);
                }
            }
            // no barrier: per-wave-private Ps rows, same-wave program order

            // ---- O += P @ V for these 64 kv
            #pragma unroll
            for (int kcl = 0; kcl < 2; ++kcl) {
                const int kc = hi * 2 + kcl;        // global 32-chunk within tile
                s8v ap[2];
                #pragma unroll
                for (int g = 0; g < 2; ++g)
                    ap[g] = *reinterpret_cast<const s8v*>(
                        Ps + (w * 32 + g * 16 + l15) * 72 + kcl * 32 + qd * 8);
                #pragma unroll
                for (int dt = 0; dt < 4; ++dt) {
                    const s8v bv = *reinterpret_cast<const s8v*>(
                        Vs + (dt * 16 + l15) * 128 + (((kc * 4 + qd) ^ l15) & 15) * 8);
                    oacc[0][dt] = __builtin_amdgcn_mfma_f32_16x16x32_bf16(ap[0], bv, oacc[0][dt], 0, 0, 0);
                    oacc[1][dt] = __builtin_amdgcn_mfma_f32_16x16x32_bf16(ap[1], bv, oacc[1][dt], 0, 0, 0);
                }
            }
        }
    }

    // ---- epilogue: store unnormalized O partial + L partial
    unsigned short* __restrict__ Oh = half ? O1 : O0;
    #pragma unroll
    for (int g = 0; g < 2; ++g) {
        float ls = lacc[g];
        ls += __shfl_xor(ls, 16);
        ls += __shfl_xor(ls, 32);            // all lanes: L for q = w*32+g*16+l15
        if (qd == 0)
            Lp[((size_t)(half * 32 + bh)) * S_ + q0 + w * 32 + g * 16 + l15] = ls;
        #pragma unroll
        for (int r = 0; r < 4; ++r) {
            const int s = q0 + w * 32 + g * 16 + qd * 4 + r;
            unsigned short* __restrict__ dst =
                Oh + ((size_t)(b * S_ + s)) * HID_ + h * HD_ + l15;
            #pragma unroll
            for (int dt = 0; dt < 4; ++dt)
                dst[dt * 16] = f2b_rne(oacc[g][dt][r]);
        }
    }
}

// ---------------------------------------------------------------------------
// Kernel: combine kv-split partials: Cb = (O0 + O1) / (L0 + L1). 8 elems/thr.
// ---------------------------------------------------------------------------
__global__ __launch_bounds__(256) void combine_kernel(
    const unsigned short* __restrict__ O0, const unsigned short* __restrict__ O1,
    const float* __restrict__ Lp, unsigned short* __restrict__ Cb)
{
    const size_t e = ((size_t)blockIdx.x * 256 + threadIdx.x) * 8;
    const int hid = (int)(e & 1023);
    const int s   = (int)((e >> 10) & 2047);
    const int b   = (int)(e >> 21);
    const int bh  = b * NH_ + (hid >> 6);
    const float L0 = Lp[(size_t)bh * S_ + s];
    const float L1 = Lp[(size_t)(32 + bh) * S_ + s];
    const float inv = 1.0f / (L0 + L1);

    const ushort4 a0 = *reinterpret_cast<const ushort4*>(O0 + e);
    const ushort4 a1 = *reinterpret_cast<const ushort4*>(O0 + e + 4);
    const ushort4 c0 = *reinterpret_cast<const ushort4*>(O1 + e);
    const ushort4 c1 = *reinterpret_cast<const ushort4*>(O1 + e + 4);
    ushort4 r0, r1;
    r0.x = f2b_rne((b2f(a0.x) + b2f(c0.x)) * inv);
    r0.y = f2b_rne((b2f(a0.y) + b2f(c0.y)) * inv);
    r0.z = f2b_rne((b2f(a0.z) + b2f(c0.z)) * inv);
    r0.w = f2b_rne((b2f(a0.w) + b2f(c0.w)) * inv);
    r1.x = f2b_rne((b2f(a1.x) + b2f(c1.x)) * inv);
    r1.y = f2b_rne((b2f(a1.y) + b2f(c1.y)) * inv);
    r1.z = f2b_rne((b2f(a1.z) + b2f(c1.z)) * inv);
    r1.w = f2b_rne((b2f(a1.w) + b2f(c1.w)) * inv);
    *reinterpret_cast<ushort4*>(Cb + e) = r0;
    *reinterpret_cast<ushort4*>(Cb + e + 4) = r1;
}

// ---------------------------------------------------------------------------
extern "C" void kernel_launch(void* const* d_in, const int* in_sizes, int n_in,
                              void* d_out, int out_size, void* d_ws, size_t ws_size,
                              hipStream_t stream)
{
    const float* X  = (const float*)d_in[0];
    const float* Wq = (const float*)d_in[1];
    const float* bq = (const float*)d_in[2];
    const float* Wk = (const float*)d_in[3];
    const float* bk = (const float*)d_in[4];
    const float* Wv = (const float*)d_in[5];
    const float* bv = (const float*)d_in[6];
    const float* Wo = (const float*)d_in[7];
    const float* bo = (const float*)d_in[8];
    float* out = (float*)d_out;

    // ws (ushort elems): Wot 1M | Xb 4M | Wqt 1M | Wkt 1M | Wvt 1M |
    //                    Qb 4M | Kb 4M | Vt 4M | Cb 4M | O1 4M        = 56 MB
    // Aliases (dead after gemm_qkv): O0 = Xb region, Lp = Wqt region.
    const size_t QKV = (size_t)B_ * NH_ * S_ * HD_;   // 4,194,304
    const size_t WSZ = (size_t)HID_ * HID_;           // 1,048,576
    unsigned short* Wot = (unsigned short*)d_ws;
    unsigned short* Xb  = Wot + WSZ;
    unsigned short* Wqt = Xb  + QKV;
    unsigned short* Wkt = Wqt + WSZ;
    unsigned short* Wvt = Wkt + WSZ;
    unsigned short* Qb  = Wvt + WSZ;
    unsigned short* Kb  = Qb + QKV;
    unsigned short* Vt  = Kb + QKV;
    unsigned short* Cb  = Vt + QKV;
    unsigned short* O1  = Cb + QKV;
    unsigned short* O0  = Xb;            // alias (Xb dead after gemm_qkv)
    float*          Lp  = (float*)Wqt;   // alias (Wqt dead after gemm_qkv), 512 KB

    prep_kernel<<<dim3(16, 16, 8), 256, 0, stream>>>(
        X, Wq, Wk, Wv, Wo, Xb, Wqt, Wkt, Wvt, Wot);
    gemm_qkv_kernel<<<dim3(8, 32, 3), 256, 0, stream>>>(
        Xb, Wqt, Wkt, Wvt, bq, bk, bv, Qb, Kb, Vt);
    attn_kernel<<<dim3(S_ / 128, B_ * NH_, 2), 256, 0, stream>>>(
        (const bf16*)Qb, (const bf16*)Kb, (const bf16*)Vt, O0, O1, Lp);
    combine_kernel<<<2048, 256, 0, stream>>>(O0, O1, Lp, Cb);
    gemm_out_kernel<<<dim3(8, 32), 256, 0, stream>>>(Cb, Wot, bo, out);
}

// Round 8
// 205.886 us; speedup vs baseline: 1.0502x; 1.0502x over previous
//
#include <hip/hip_runtime.h>
#include <hip/hip_bf16.h>

// Problem constants (fixed by reference)
#define B_   2
#define S_   2048
#define HID_ 1024
#define NH_  16
#define HD_  64

typedef __hip_bfloat16 bf16;
typedef __attribute__((ext_vector_type(8))) short s8v;   // 8 bf16 (MFMA K=32 A/B frag)
typedef __attribute__((ext_vector_type(4))) short s4v;   // 4 bf16 (MFMA K=16 A/B frag)
typedef __attribute__((ext_vector_type(4))) float f4v;   // MFMA C/D frag

// Q pre-scale: 0.125 (1/sqrt(64)) * log2(e) -> exp2(score) == exp(q.k/8) exactly
#define QSCALE 0.18033688011112042f

__device__ __forceinline__ unsigned short f2b_rne(float x) {
    unsigned int u = __float_as_uint(x);
    u += 0x7fffu + ((u >> 16) & 1u);
    return (unsigned short)(u >> 16);
}

__device__ __forceinline__ void gload_lds16(const void* g, void* l) {
    __builtin_amdgcn_global_load_lds(
        (const __attribute__((address_space(1))) void*)g,
        (__attribute__((address_space(3))) void*)l, 16, 0, 0);
}

// pack 4 fp32 -> 4 bf16 (truncation) as a K=16 A-frag, 2 v_perm ops
__device__ __forceinline__ s4v pack_p(float p0, float p1, float p2, float p3) {
    union { uint2 u; s4v s; } c;
    c.u.x = __builtin_amdgcn_perm(__float_as_uint(p1), __float_as_uint(p0), 0x07060302u);
    c.u.y = __builtin_amdgcn_perm(__float_as_uint(p3), __float_as_uint(p2), 0x07060302u);
    return c.s;
}

// ---------------------------------------------------------------------------
// Prep: z=0..3 -> transpose W_z fp32 [k][n] -> bf16 [n][k]; z=4..7 -> convert
// a quarter of X fp32 -> bf16 (layout-preserving). grid (16,16,8), 256 thr.
// ---------------------------------------------------------------------------
__global__ __launch_bounds__(256) void prep_kernel(
    const float* __restrict__ X,
    const float* __restrict__ W0, const float* __restrict__ W1,
    const float* __restrict__ W2, const float* __restrict__ W3,
    unsigned short* __restrict__ Xb,
    unsigned short* __restrict__ T0, unsigned short* __restrict__ T1,
    unsigned short* __restrict__ T2, unsigned short* __restrict__ T3)
{
    const int z = blockIdx.z;
    const int t = threadIdx.x;

    if (z >= 4) {
        const size_t base = ((size_t)(z - 4) * 256 + blockIdx.y * 16 + blockIdx.x) * 4096;
        #pragma unroll
        for (int p = 0; p < 4; ++p) {
            const size_t i = base + p * 1024 + t * 4;
            const float4 f = *reinterpret_cast<const float4*>(X + i);
            ushort4 u;
            u.x = f2b_rne(f.x); u.y = f2b_rne(f.y); u.z = f2b_rne(f.z); u.w = f2b_rne(f.w);
            *reinterpret_cast<ushort4*>(Xb + i) = u;
        }
        return;
    }

    const float* __restrict__ W = (z == 0) ? W0 : (z == 1) ? W1 : (z == 2) ? W2 : W3;
    unsigned short* __restrict__ T = (z == 0) ? T0 : (z == 1) ? T1 : (z == 2) ? T2 : T3;

    __shared__ float Tl[64][65];
    const int n0 = blockIdx.x * 64, k0 = blockIdx.y * 64;
    const int rr = t >> 4, c4 = (t & 15) * 4;

    #pragma unroll
    for (int i = 0; i < 4; ++i) {
        const int kr = i * 16 + rr;
        const float4 f = *reinterpret_cast<const float4*>(W + (size_t)(k0 + kr) * HID_ + n0 + c4);
        Tl[c4 + 0][kr] = f.x; Tl[c4 + 1][kr] = f.y;
        Tl[c4 + 2][kr] = f.z; Tl[c4 + 3][kr] = f.w;
    }
    __syncthreads();
    #pragma unroll
    for (int i = 0; i < 4; ++i) {
        const int nr = i * 16 + rr;
        ushort4 u;
        u.x = f2b_rne(Tl[nr][c4 + 0]); u.y = f2b_rne(Tl[nr][c4 + 1]);
        u.z = f2b_rne(Tl[nr][c4 + 2]); u.w = f2b_rne(Tl[nr][c4 + 3]);
        *reinterpret_cast<ushort4*>(T + (size_t)(n0 + nr) * HID_ + k0 + c4) = u;
    }
}

// ---------------------------------------------------------------------------
// Shared MFMA mainloop: 128x128 tile, BK=64, 4 waves 2x2, global_load_lds
// staging with XOR chunk swizzle. A [m][k], Bt [n][k], both bf16 k-major.
// ---------------------------------------------------------------------------
__device__ __forceinline__ void mfma_mainloop(
    const unsigned short* __restrict__ Ag, const unsigned short* __restrict__ Bg,
    unsigned short* As, unsigned short* Bs,
    int m0, int n0, int t, f4v acc[4][4])
{
    const int w = t >> 6, lane = t & 63;
    const int l15 = lane & 15, qd = lane >> 4;
    const int wm = (w & 1) * 64, wn = (w >> 1) * 64;
    const int srow = w * 8 + (lane >> 3);
    const int lc8  = (((lane & 7) ^ (lane >> 3)) * 8);

    for (int k0 = 0; k0 < HID_; k0 += 64) {
        __syncthreads();
        #pragma unroll
        for (int it = 0; it < 4; ++it) {
            const int row = it * 32 + srow;
            const int sb = (it * 256 + w * 64) * 8;
            gload_lds16(Ag + (size_t)(m0 + row) * HID_ + k0 + lc8, As + sb);
            gload_lds16(Bg + (size_t)(n0 + row) * HID_ + k0 + lc8, Bs + sb);
        }
        __syncthreads();
        #pragma unroll
        for (int kc = 0; kc < 2; ++kc) {
            const int p = ((kc * 4 + qd) ^ (l15 & 7)) * 8;
            s8v af[4], bf[4];
            #pragma unroll
            for (int mt = 0; mt < 4; ++mt)
                af[mt] = *reinterpret_cast<const s8v*>(As + (wm + mt * 16 + l15) * 64 + p);
            #pragma unroll
            for (int nt = 0; nt < 4; ++nt)
                bf[nt] = *reinterpret_cast<const s8v*>(Bs + (wn + nt * 16 + l15) * 64 + p);
            #pragma unroll
            for (int mt = 0; mt < 4; ++mt)
                #pragma unroll
                for (int nt = 0; nt < 4; ++nt)
                    acc[mt][nt] = __builtin_amdgcn_mfma_f32_16x16x32_bf16(
                        af[mt], bf[nt], acc[mt][nt], 0, 0, 0);
        }
    }
}

// ---------------------------------------------------------------------------
// Kernel: QKV projection GEMM + bias + axial RoPE epilogue.
// Q is additionally pre-scaled by QSCALE (softmax exp2 fold).
// ---------------------------------------------------------------------------
__global__ __launch_bounds__(256) void gemm_qkv_kernel(
    const unsigned short* __restrict__ Xb,
    const unsigned short* __restrict__ Wqt, const unsigned short* __restrict__ Wkt,
    const unsigned short* __restrict__ Wvt,
    const float* __restrict__ bq, const float* __restrict__ bk, const float* __restrict__ bv,
    unsigned short* __restrict__ Qb, unsigned short* __restrict__ Kb,
    unsigned short* __restrict__ Vt)
{
    const int z = blockIdx.z;
    const unsigned short* __restrict__ Bt = (z == 0) ? Wqt : (z == 1) ? Wkt : Wvt;
    const float* __restrict__ bias = (z == 0) ? bq : (z == 1) ? bk : bv;

    const int n0 = blockIdx.x * 128, m0 = blockIdx.y * 128;
    const int t = threadIdx.x;
    const int w = t >> 6, lane = t & 63;
    const int l15 = lane & 15, qd = lane >> 4;
    const int wm = (w & 1) * 64, wn = (w >> 1) * 64;

    __shared__ unsigned short As[128 * 64];
    __shared__ unsigned short Bs[128 * 64];

    f4v acc[4][4];
    #pragma unroll
    for (int mt = 0; mt < 4; ++mt)
        #pragma unroll
        for (int nt = 0; nt < 4; ++nt) acc[mt][nt] = (f4v){0.f, 0.f, 0.f, 0.f};

    mfma_mainloop(Xb, Bt, As, Bs, m0, n0, t, acc);

    const float osc = (z == 0) ? QSCALE : 1.f;

    #pragma unroll
    for (int nt = 0; nt < 4; ++nt) {
        const int col = n0 + wn + nt * 16 + l15;   // 0..1023
        const int h = col >> 6, d = col & 63;
        const float bsc = bias[col];
        const int seg = d / 20;
        const int ds  = d - seg * 20;
        const float om   = __expf(-0.9210340372f * (float)(ds % 10));
        const float sign = (d & 1) ? 1.f : -1.f;

        #pragma unroll
        for (int mt = 0; mt < 4; ++mt) {
            const int mbase = m0 + wm + mt * 16 + qd * 4;
            const int b = mbase >> 11;
            const int sbase = mbase & 2047;
            if (z == 2) {
                ushort4 u;
                unsigned short* up = (unsigned short*)&u;
                #pragma unroll
                for (int r = 0; r < 4; ++r) up[r] = f2b_rne(acc[mt][nt][r] + bsc);
                *reinterpret_cast<ushort4*>(
                    Vt + ((size_t)(b * NH_ + h) * HD_ + d) * S_ + sbase) = u;
            } else {
                unsigned short* __restrict__ dst = (z == 0 ? Qb : Kb)
                    + ((size_t)(b * NH_ + h) * S_ + sbase) * HD_ + d;
                #pragma unroll
                for (int r = 0; r < 4; ++r) {
                    const int s = sbase + r;
                    float v = acc[mt][nt][r] + bsc;
                    const float xp = __shfl_xor(v, 1);
                    if (d < 60) {
                        const int rem = s & 255;
                        const float pos = (float)(seg == 0 ? (s >> 8)
                                               : (seg == 1 ? (rem >> 4) : (rem & 15)));
                        const float a = pos * om;
                        float sn, cs;
                        __sincosf(a, &sn, &cs);
                        v = v * cs + sign * xp * sn;
                    }
                    dst[(size_t)r * HD_] = f2b_rne(v * osc);
                }
            }
        }
    }
}

// ---------------------------------------------------------------------------
// Kernel: output projection GEMM + bias -> fp32 out. grid (8, 32).
// ---------------------------------------------------------------------------
__global__ __launch_bounds__(256) void gemm_out_kernel(
    const unsigned short* __restrict__ Cb, const unsigned short* __restrict__ Wot,
    const float* __restrict__ bo, float* __restrict__ out)
{
    const int n0 = blockIdx.x * 128, m0 = blockIdx.y * 128;
    const int t = threadIdx.x;
    const int w = t >> 6, lane = t & 63;
    const int l15 = lane & 15, qd = lane >> 4;
    const int wm = (w & 1) * 64, wn = (w >> 1) * 64;

    __shared__ unsigned short As[128 * 64];
    __shared__ unsigned short Bs[128 * 64];

    f4v acc[4][4];
    #pragma unroll
    for (int mt = 0; mt < 4; ++mt)
        #pragma unroll
        for (int nt = 0; nt < 4; ++nt) acc[mt][nt] = (f4v){0.f, 0.f, 0.f, 0.f};

    mfma_mainloop(Cb, Wot, As, Bs, m0, n0, t, acc);

    #pragma unroll
    for (int nt = 0; nt < 4; ++nt) {
        const int col = n0 + wn + nt * 16 + l15;
        const float bsc = bo[col];
        #pragma unroll
        for (int mt = 0; mt < 4; ++mt) {
            const int mbase = m0 + wm + mt * 16 + qd * 4;
            #pragma unroll
            for (int r = 0; r < 4; ++r)
                out[(size_t)(mbase + r) * HID_ + col] = acc[mt][nt][r] + bsc;
        }
    }
}

// ---------------------------------------------------------------------------
// Kernel: MFMA flash attention v5 — P in registers, double-buffered staging.
// Block = 4 waves, 128 q rows (wave w: q [w*32, w*32+32), groups g=0,1).
// Per 128-kv tile:
//   scores TRANSPOSED: D[kv][q] via mfma_16x16x32 (A=K from LDS, B=Q regs)
//   p = exp2(score), packed bf16 -> the C-layout IS the K=16 A-layout:
//   PV via mfma_f32_16x16x16_bf16 (A=P regs, B=V b64 from LDS) -- no P LDS!
//   l via one extra K16 MFMA against ones (consistent, row-aligned with O)
// Staging: global_load_lds double-buffer, raw s_barrier + own vmcnt wait
// (no __syncthreads -> no compiler drain; prefetch stays in flight).
// LDS 2*(16+16) KB = 64 KB -> 2 blocks/CU.
// ---------------------------------------------------------------------------
__global__ __launch_bounds__(256, 2) void attn_kernel(
    const bf16* __restrict__ Qb, const bf16* __restrict__ Kb,
    const bf16* __restrict__ Vt, unsigned short* __restrict__ Cb)
{
    const int q0 = blockIdx.x * 128;
    const int bh = blockIdx.y;
    const int b  = bh >> 4, h = bh & 15;
    const int t  = threadIdx.x;
    const int w  = t >> 6;
    const int lane = t & 63;
    const int l15 = lane & 15, qd = lane >> 4;

    __shared__ unsigned short Ks[2][128 * 64];   // [kv][d], chunks XOR kv&7
    __shared__ unsigned short Vs[2][64 * 128];   // [d][kv], chunks XOR d&15

    // Q B-frags (pre-scaled by QSCALE in the projection epilogue)
    s8v bq[2][2];
    #pragma unroll
    for (int g = 0; g < 2; ++g) {
        const bf16* Qrow = Qb + ((size_t)bh * S_ + q0 + w * 32 + g * 16 + l15) * HD_ + qd * 8;
        bq[g][0] = *reinterpret_cast<const s8v*>(Qrow);
        bq[g][1] = *reinterpret_cast<const s8v*>(Qrow + 32);
    }

    f4v oacc[2][4];
    f4v lones[2];
    #pragma unroll
    for (int g = 0; g < 2; ++g) {
        lones[g] = (f4v){0.f, 0.f, 0.f, 0.f};
        #pragma unroll
        for (int dt = 0; dt < 4; ++dt) oacc[g][dt] = (f4v){0.f, 0.f, 0.f, 0.f};
    }

    s4v vone;
    { union { uint2 u; s4v s; } c; c.u = make_uint2(0x3F803F80u, 0x3F803F80u); vone = c.s; }

    const bf16* __restrict__ Kg = Kb + (size_t)bh * S_ * HD_;
    const bf16* __restrict__ Vg = Vt + (size_t)bh * HD_ * S_;

    const int krow = lane >> 3;                     // 0..7
    const int ksw  = ((lane & 7) ^ krow) * 8;       // K source chunk swizzle
    const int vrow = lane >> 4;                     // 0..3

    auto stage = [&](int tile, unsigned short* Kd, unsigned short* Vd) {
        const int k0 = tile * 128;
        #pragma unroll
        for (int it = 0; it < 4; ++it) {
            gload_lds16(Kg + (size_t)(k0 + w * 32 + it * 8 + krow) * HD_ + ksw,
                        Kd + (w * 32 + it * 8) * 64);
        }
        #pragma unroll
        for (int it = 0; it < 4; ++it) {
            const int r = w * 16 + it * 4 + vrow;
            const int sv = ((lane & 15) ^ (r & 15)) * 8;
            gload_lds16(Vg + (size_t)r * S_ + k0 + sv,
                        Vd + (w * 16 + it * 4) * 128);
        }
    };

    stage(0, Ks[0], Vs[0]);   // prologue prefetch

    for (int tt = 0; tt < S_ / 128; ++tt) {
        __builtin_amdgcn_s_waitcnt(0x0f70);   // vmcnt(0): own tile-tt loads done
        __builtin_amdgcn_s_barrier();         // raw barrier: all waves staged tt
        if (tt < S_ / 128 - 1)
            stage(tt + 1, Ks[(tt + 1) & 1], Vs[(tt + 1) & 1]);

        const unsigned short* K_ = Ks[tt & 1];
        const unsigned short* V_ = Vs[tt & 1];

        #pragma unroll
        for (int nt = 0; nt < 8; ++nt) {
            const unsigned short* kr = K_ + (nt * 16 + l15) * 64;
            const s8v ak0 = *reinterpret_cast<const s8v*>(kr + ((qd ^ (l15 & 7)) * 8));
            const s8v ak1 = *reinterpret_cast<const s8v*>(kr + (((qd + 4) ^ (l15 & 7)) * 8));

            // V B-frags for K=16 PV: B[k=kv=nt*16+qd*4+j][n=d=dt*16+l15]
            s4v bv[4];
            #pragma unroll
            for (int dt = 0; dt < 4; ++dt) {
                const int r = dt * 16 + l15;
                const int c = nt * 2 + (qd >> 1);           // source kv chunk
                bv[dt] = *reinterpret_cast<const s4v*>(
                    V_ + r * 128 + ((c ^ l15) & 15) * 8 + (qd & 1) * 4);
            }

            #pragma unroll
            for (int g = 0; g < 2; ++g) {
                f4v zz = (f4v){0.f, 0.f, 0.f, 0.f};
                zz = __builtin_amdgcn_mfma_f32_16x16x32_bf16(ak0, bq[g][0], zz, 0, 0, 0);
                zz = __builtin_amdgcn_mfma_f32_16x16x32_bf16(ak1, bq[g][1], zz, 0, 0, 0);
                const float p0 = __builtin_amdgcn_exp2f(zz[0]);
                const float p1 = __builtin_amdgcn_exp2f(zz[1]);
                const float p2 = __builtin_amdgcn_exp2f(zz[2]);
                const float p3 = __builtin_amdgcn_exp2f(zz[3]);
                const s4v pf = pack_p(p0, p1, p2, p3);      // K=16 A-frag, direct
                #pragma unroll
                for (int dt = 0; dt < 4; ++dt)
                    oacc[g][dt] = __builtin_amdgcn_mfma_f32_16x16x16bf16_1k(
                        pf, bv[dt], oacc[g][dt], 0, 0, 0);
                lones[g] = __builtin_amdgcn_mfma_f32_16x16x16bf16_1k(
                    pf, vone, lones[g], 0, 0, 0);           // l row-sums, aligned with oacc
            }
        }
    }

    // ---- epilogue: O[q=qd*4+r][d=dt*16+l15] / l[q]; l aligned, no shuffles
    #pragma unroll
    for (int g = 0; g < 2; ++g) {
        #pragma unroll
        for (int r = 0; r < 4; ++r) {
            const float inv = 1.0f / lones[g][r];
            const int s = q0 + w * 32 + g * 16 + qd * 4 + r;
            unsigned short* __restrict__ dst =
                Cb + ((size_t)(b * S_ + s)) * HID_ + h * HD_ + l15;
            #pragma unroll
            for (int dt = 0; dt < 4; ++dt)
                dst[dt * 16] = f2b_rne(oacc[g][dt][r] * inv);
        }
    }
}

// ---------------------------------------------------------------------------
extern "C" void kernel_launch(void* const* d_in, const int* in_sizes, int n_in,
                              void* d_out, int out_size, void* d_ws, size_t ws_size,
                              hipStream_t stream)
{
    const float* X  = (const float*)d_in[0];
    const float* Wq = (const float*)d_in[1];
    const float* bq = (const float*)d_in[2];
    const float* Wk = (const float*)d_in[3];
    const float* bk = (const float*)d_in[4];
    const float* Wv = (const float*)d_in[5];
    const float* bv = (const float*)d_in[6];
    const float* Wo = (const float*)d_in[7];
    const float* bo = (const float*)d_in[8];
    float* out = (float*)d_out;

    // ws (ushort elems): Wot 1M | Xb 4M | Wqt 1M | Wkt 1M | Wvt 1M |
    //                    Qb 4M | Kb 4M | Vt 4M | Cb 4M = 48 MB
    const size_t QKV = (size_t)B_ * NH_ * S_ * HD_;   // 4,194,304
    const size_t WSZ = (size_t)HID_ * HID_;           // 1,048,576
    unsigned short* Wot = (unsigned short*)d_ws;
    unsigned short* Xb  = Wot + WSZ;
    unsigned short* Wqt = Xb  + QKV;
    unsigned short* Wkt = Wqt + WSZ;
    unsigned short* Wvt = Wkt + WSZ;
    unsigned short* Qb  = Wvt + WSZ;
    unsigned short* Kb  = Qb + QKV;
    unsigned short* Vt  = Kb + QKV;
    unsigned short* Cb  = Vt + QKV;

    prep_kernel<<<dim3(16, 16, 8), 256, 0, stream>>>(
        X, Wq, Wk, Wv, Wo, Xb, Wqt, Wkt, Wvt, Wot);
    gemm_qkv_kernel<<<dim3(8, 32, 3), 256, 0, stream>>>(
        Xb, Wqt, Wkt, Wvt, bq, bk, bv, Qb, Kb, Vt);
    attn_kernel<<<dim3(S_ / 128, B_ * NH_), 256, 0, stream>>>(
        (const bf16*)Qb, (const bf16*)Kb, (const bf16*)Vt, Cb);
    gemm_out_kernel<<<dim3(8, 32), 256, 0, stream>>>(Cb, Wot, bo, out);
}

// Round 10
// 190.471 us; speedup vs baseline: 1.1352x; 1.0809x over previous
//
#include <hip/hip_runtime.h>
#include <hip/hip_bf16.h>

// Problem constants (fixed by reference)
#define B_   2
#define S_   2048
#define HID_ 1024
#define NH_  16
#define HD_  64

typedef __hip_bfloat16 bf16;
typedef __attribute__((ext_vector_type(8))) short s8v;   // 8 bf16 (MFMA K=32 A/B frag)
typedef __attribute__((ext_vector_type(4))) short s4v;   // 4 bf16 (MFMA K=16 A/B frag)
typedef __attribute__((ext_vector_type(4))) float f4v;   // MFMA C/D frag

// Q pre-scale: 0.125 (1/sqrt(64)) * log2(e) -> exp2(score) == exp(q.k/8) exactly
#define QSCALE 0.18033688011112042f

__device__ __forceinline__ unsigned short f2b_rne(float x) {
    unsigned int u = __float_as_uint(x);
    u += 0x7fffu + ((u >> 16) & 1u);
    return (unsigned short)(u >> 16);
}

__device__ __forceinline__ void gload_lds16(const void* g, void* l) {
    __builtin_amdgcn_global_load_lds(
        (const __attribute__((address_space(1))) void*)g,
        (__attribute__((address_space(3))) void*)l, 16, 0, 0);
}

// pack 4 fp32 -> 4 bf16 (truncation) as a K=16 A-frag, 2 v_perm ops
__device__ __forceinline__ s4v pack_p(float p0, float p1, float p2, float p3) {
    union { uint2 u; s4v s; } c;
    c.u.x = __builtin_amdgcn_perm(__float_as_uint(p1), __float_as_uint(p0), 0x07060302u);
    c.u.y = __builtin_amdgcn_perm(__float_as_uint(p3), __float_as_uint(p2), 0x07060302u);
    return c.s;
}

// ---------------------------------------------------------------------------
// Prep: z=0..3 -> transpose W_z fp32 [k][n] -> bf16 [n][k]; z=4..7 -> convert
// a quarter of X fp32 -> bf16 (layout-preserving). grid (16,16,8), 256 thr.
// ---------------------------------------------------------------------------
__global__ __launch_bounds__(256) void prep_kernel(
    const float* __restrict__ X,
    const float* __restrict__ W0, const float* __restrict__ W1,
    const float* __restrict__ W2, const float* __restrict__ W3,
    unsigned short* __restrict__ Xb,
    unsigned short* __restrict__ T0, unsigned short* __restrict__ T1,
    unsigned short* __restrict__ T2, unsigned short* __restrict__ T3)
{
    const int z = blockIdx.z;
    const int t = threadIdx.x;

    if (z >= 4) {
        const size_t base = ((size_t)(z - 4) * 256 + blockIdx.y * 16 + blockIdx.x) * 4096;
        #pragma unroll
        for (int p = 0; p < 4; ++p) {
            const size_t i = base + p * 1024 + t * 4;
            const float4 f = *reinterpret_cast<const float4*>(X + i);
            ushort4 u;
            u.x = f2b_rne(f.x); u.y = f2b_rne(f.y); u.z = f2b_rne(f.z); u.w = f2b_rne(f.w);
            *reinterpret_cast<ushort4*>(Xb + i) = u;
        }
        return;
    }

    const float* __restrict__ W = (z == 0) ? W0 : (z == 1) ? W1 : (z == 2) ? W2 : W3;
    unsigned short* __restrict__ T = (z == 0) ? T0 : (z == 1) ? T1 : (z == 2) ? T2 : T3;

    __shared__ float Tl[64][65];
    const int n0 = blockIdx.x * 64, k0 = blockIdx.y * 64;
    const int rr = t >> 4, c4 = (t & 15) * 4;

    #pragma unroll
    for (int i = 0; i < 4; ++i) {
        const int kr = i * 16 + rr;
        const float4 f = *reinterpret_cast<const float4*>(W + (size_t)(k0 + kr) * HID_ + n0 + c4);
        Tl[c4 + 0][kr] = f.x; Tl[c4 + 1][kr] = f.y;
        Tl[c4 + 2][kr] = f.z; Tl[c4 + 3][kr] = f.w;
    }
    __syncthreads();
    #pragma unroll
    for (int i = 0; i < 4; ++i) {
        const int nr = i * 16 + rr;
        ushort4 u;
        u.x = f2b_rne(Tl[nr][c4 + 0]); u.y = f2b_rne(Tl[nr][c4 + 1]);
        u.z = f2b_rne(Tl[nr][c4 + 2]); u.w = f2b_rne(Tl[nr][c4 + 3]);
        *reinterpret_cast<ushort4*>(T + (size_t)(n0 + nr) * HID_ + k0 + c4) = u;
    }
}

// ---------------------------------------------------------------------------
// Double-buffered MFMA mainloop: 128x128 tile, BK=64, 4 waves 2x2.
// Raw s_barrier + per-wave vmcnt(0) (attn-v5 pattern): one barrier per
// k-iter, prefetch of tile k+1 in flight across the whole compute phase.
// A [m][k], Bt [n][k], both bf16 k-major, XOR chunk swizzle.
// ---------------------------------------------------------------------------
__device__ __forceinline__ void gemm_stage(
    const unsigned short* __restrict__ Ag, const unsigned short* __restrict__ Bg,
    unsigned short* As, unsigned short* Bs,
    int m0, int n0, int k0, int w, int srow, int lc8)
{
    #pragma unroll
    for (int it = 0; it < 4; ++it) {
        const int row = it * 32 + srow;
        const int sb = (it * 256 + w * 64) * 8;
        gload_lds16(Ag + (size_t)(m0 + row) * HID_ + k0 + lc8, As + sb);
        gload_lds16(Bg + (size_t)(n0 + row) * HID_ + k0 + lc8, Bs + sb);
    }
}

__device__ __forceinline__ void mfma_mainloop_db(
    const unsigned short* __restrict__ Ag, const unsigned short* __restrict__ Bg,
    unsigned short (*As)[128 * 64], unsigned short (*Bs)[128 * 64],
    int m0, int n0, int t, f4v acc[4][4])
{
    const int w = t >> 6, lane = t & 63;
    const int l15 = lane & 15, qd = lane >> 4;
    const int wm = (w & 1) * 64, wn = (w >> 1) * 64;
    const int srow = w * 8 + (lane >> 3);
    const int lc8  = (((lane & 7) ^ (lane >> 3)) * 8);

    gemm_stage(Ag, Bg, As[0], Bs[0], m0, n0, 0, w, srow, lc8);

    for (int kt = 0; kt < HID_ / 64; ++kt) {
        __builtin_amdgcn_s_waitcnt(0x0f70);   // vmcnt(0): own tile-kt loads done
        __builtin_amdgcn_s_barrier();         // all waves staged tile kt
        if (kt < HID_ / 64 - 1)
            gemm_stage(Ag, Bg, As[(kt + 1) & 1], Bs[(kt + 1) & 1],
                       m0, n0, (kt + 1) * 64, w, srow, lc8);

        const unsigned short* Acur = As[kt & 1];
        const unsigned short* Bcur = Bs[kt & 1];
        #pragma unroll
        for (int kc = 0; kc < 2; ++kc) {
            const int p = ((kc * 4 + qd) ^ (l15 & 7)) * 8;
            s8v af[4], bf[4];
            #pragma unroll
            for (int mt = 0; mt < 4; ++mt)
                af[mt] = *reinterpret_cast<const s8v*>(Acur + (wm + mt * 16 + l15) * 64 + p);
            #pragma unroll
            for (int nt = 0; nt < 4; ++nt)
                bf[nt] = *reinterpret_cast<const s8v*>(Bcur + (wn + nt * 16 + l15) * 64 + p);
            #pragma unroll
            for (int mt = 0; mt < 4; ++mt)
                #pragma unroll
                for (int nt = 0; nt < 4; ++nt)
                    acc[mt][nt] = __builtin_amdgcn_mfma_f32_16x16x32_bf16(
                        af[mt], bf[nt], acc[mt][nt], 0, 0, 0);
        }
    }
}

// ---------------------------------------------------------------------------
// Kernel: fused QKV projection GEMM + bias + axial RoPE epilogue.
// grid (24 n-tiles over concatenated Wq|Wk|Wv [3072][1024], 32 m-tiles).
// z = n-tile>>3 selects Q/K/V role (block-uniform). Q pre-scaled by QSCALE.
// ---------------------------------------------------------------------------
__global__ __launch_bounds__(256, 2) void gemm_qkv_kernel(
    const unsigned short* __restrict__ Xb, const unsigned short* __restrict__ Wt,
    const float* __restrict__ bq, const float* __restrict__ bk, const float* __restrict__ bv,
    unsigned short* __restrict__ Qb, unsigned short* __restrict__ Kb,
    unsigned short* __restrict__ Vt)
{
    const int n0g = blockIdx.x * 128;          // 0..3071 (concatenated)
    const int z   = n0g >> 10;                 // 0=Q, 1=K, 2=V (block-uniform)
    const int n0  = n0g & 1023;                // within this projection
    const int m0  = blockIdx.y * 128;
    const float* __restrict__ bias = (z == 0) ? bq : (z == 1) ? bk : bv;

    const int t = threadIdx.x;
    const int w = t >> 6, lane = t & 63;
    const int l15 = lane & 15, qd = lane >> 4;
    const int wm = (w & 1) * 64, wn = (w >> 1) * 64;

    __shared__ unsigned short As[2][128 * 64];
    __shared__ unsigned short Bs[2][128 * 64];

    f4v acc[4][4];
    #pragma unroll
    for (int mt = 0; mt < 4; ++mt)
        #pragma unroll
        for (int nt = 0; nt < 4; ++nt) acc[mt][nt] = (f4v){0.f, 0.f, 0.f, 0.f};

    mfma_mainloop_db(Xb, Wt, As, Bs, m0, n0g, t, acc);

    const float osc = (z == 0) ? QSCALE : 1.f;

    #pragma unroll
    for (int nt = 0; nt < 4; ++nt) {
        const int col = n0 + wn + nt * 16 + l15;   // 0..1023
        const int h = col >> 6, d = col & 63;
        const float bsc = bias[col];
        const int seg = d / 20;
        const int ds  = d - seg * 20;
        const float om   = __expf(-0.9210340372f * (float)(ds % 10));
        const float sign = (d & 1) ? 1.f : -1.f;

        #pragma unroll
        for (int mt = 0; mt < 4; ++mt) {
            const int mbase = m0 + wm + mt * 16 + qd * 4;
            const int b = mbase >> 11;
            const int sbase = mbase & 2047;
            if (z == 2) {
                ushort4 u;
                unsigned short* up = (unsigned short*)&u;
                #pragma unroll
                for (int r = 0; r < 4; ++r) up[r] = f2b_rne(acc[mt][nt][r] + bsc);
                *reinterpret_cast<ushort4*>(
                    Vt + ((size_t)(b * NH_ + h) * HD_ + d) * S_ + sbase) = u;
            } else {
                unsigned short* __restrict__ dst = (z == 0 ? Qb : Kb)
                    + ((size_t)(b * NH_ + h) * S_ + sbase) * HD_ + d;
                #pragma unroll
                for (int r = 0; r < 4; ++r) {
                    const int s = sbase + r;
                    float v = acc[mt][nt][r] + bsc;
                    const float xp = __shfl_xor(v, 1);
                    if (d < 60) {
                        const int rem = s & 255;
                        const float pos = (float)(seg == 0 ? (s >> 8)
                                               : (seg == 1 ? (rem >> 4) : (rem & 15)));
                        const float a = pos * om;
                        float sn, cs;
                        __sincosf(a, &sn, &cs);
                        v = v * cs + sign * xp * sn;
                    }
                    dst[(size_t)r * HD_] = f2b_rne(v * osc);
                }
            }
        }
    }
}

// ---------------------------------------------------------------------------
// Kernel: output projection GEMM + bias -> fp32 out. grid (8, 32).
// ---------------------------------------------------------------------------
__global__ __launch_bounds__(256, 2) void gemm_out_kernel(
    const unsigned short* __restrict__ Cb, const unsigned short* __restrict__ Wot,
    const float* __restrict__ bo, float* __restrict__ out)
{
    const int n0 = blockIdx.x * 128, m0 = blockIdx.y * 128;
    const int t = threadIdx.x;
    const int w = t >> 6, lane = t & 63;
    const int l15 = lane & 15, qd = lane >> 4;
    const int wm = (w & 1) * 64, wn = (w >> 1) * 64;

    __shared__ unsigned short As[2][128 * 64];
    __shared__ unsigned short Bs[2][128 * 64];

    f4v acc[4][4];
    #pragma unroll
    for (int mt = 0; mt < 4; ++mt)
        #pragma unroll
        for (int nt = 0; nt < 4; ++nt) acc[mt][nt] = (f4v){0.f, 0.f, 0.f, 0.f};

    mfma_mainloop_db(Cb, Wot, As, Bs, m0, n0, t, acc);

    #pragma unroll
    for (int nt = 0; nt < 4; ++nt) {
        const int col = n0 + wn + nt * 16 + l15;
        const float bsc = bo[col];
        #pragma unroll
        for (int mt = 0; mt < 4; ++mt) {
            const int mbase = m0 + wm + mt * 16 + qd * 4;
            #pragma unroll
            for (int r = 0; r < 4; ++r)
                out[(size_t)(mbase + r) * HID_ + col] = acc[mt][nt][r] + bsc;
        }
    }
}

// ---------------------------------------------------------------------------
// Kernel: MFMA flash attention v5 — P in registers, double-buffered staging.
// (unchanged from R8 — it fell off the top-5)
// ---------------------------------------------------------------------------
__global__ __launch_bounds__(256, 2) void attn_kernel(
    const bf16* __restrict__ Qb, const bf16* __restrict__ Kb,
    const bf16* __restrict__ Vt, unsigned short* __restrict__ Cb)
{
    const int q0 = blockIdx.x * 128;
    const int bh = blockIdx.y;
    const int b  = bh >> 4, h = bh & 15;
    const int t  = threadIdx.x;
    const int w  = t >> 6;
    const int lane = t & 63;
    const int l15 = lane & 15, qd = lane >> 4;

    __shared__ unsigned short Ks[2][128 * 64];   // [kv][d], chunks XOR kv&7
    __shared__ unsigned short Vs[2][64 * 128];   // [d][kv], chunks XOR d&15

    s8v bq[2][2];
    #pragma unroll
    for (int g = 0; g < 2; ++g) {
        const bf16* Qrow = Qb + ((size_t)bh * S_ + q0 + w * 32 + g * 16 + l15) * HD_ + qd * 8;
        bq[g][0] = *reinterpret_cast<const s8v*>(Qrow);
        bq[g][1] = *reinterpret_cast<const s8v*>(Qrow + 32);
    }

    f4v oacc[2][4];
    f4v lones[2];
    #pragma unroll
    for (int g = 0; g < 2; ++g) {
        lones[g] = (f4v){0.f, 0.f, 0.f, 0.f};
        #pragma unroll
        for (int dt = 0; dt < 4; ++dt) oacc[g][dt] = (f4v){0.f, 0.f, 0.f, 0.f};
    }

    s4v vone;
    { union { uint2 u; s4v s; } c; c.u = make_uint2(0x3F803F80u, 0x3F803F80u); vone = c.s; }

    const bf16* __restrict__ Kg = Kb + (size_t)bh * S_ * HD_;
    const bf16* __restrict__ Vg = Vt + (size_t)bh * HD_ * S_;

    const int krow = lane >> 3;
    const int ksw  = ((lane & 7) ^ krow) * 8;
    const int vrow = lane >> 4;

    auto stage = [&](int tile, unsigned short* Kd, unsigned short* Vd) {
        const int k0 = tile * 128;
        #pragma unroll
        for (int it = 0; it < 4; ++it) {
            gload_lds16(Kg + (size_t)(k0 + w * 32 + it * 8 + krow) * HD_ + ksw,
                        Kd + (w * 32 + it * 8) * 64);
        }
        #pragma unroll
        for (int it = 0; it < 4; ++it) {
            const int r = w * 16 + it * 4 + vrow;
            const int sv = ((lane & 15) ^ (r & 15)) * 8;
            gload_lds16(Vg + (size_t)r * S_ + k0 + sv,
                        Vd + (w * 16 + it * 4) * 128);
        }
    };

    stage(0, Ks[0], Vs[0]);

    for (int tt = 0; tt < S_ / 128; ++tt) {
        __builtin_amdgcn_s_waitcnt(0x0f70);
        __builtin_amdgcn_s_barrier();
        if (tt < S_ / 128 - 1)
            stage(tt + 1, Ks[(tt + 1) & 1], Vs[(tt + 1) & 1]);

        const unsigned short* K_ = Ks[tt & 1];
        const unsigned short* V_ = Vs[tt & 1];

        #pragma unroll
        for (int nt = 0; nt < 8; ++nt) {
            const unsigned short* kr = K_ + (nt * 16 + l15) * 64;
            const s8v ak0 = *reinterpret_cast<const s8v*>(kr + ((qd ^ (l15 & 7)) * 8));
            const s8v ak1 = *reinterpret_cast<const s8v*>(kr + (((qd + 4) ^ (l15 & 7)) * 8));

            s4v bv[4];
            #pragma unroll
            for (int dt = 0; dt < 4; ++dt) {
                const int r = dt * 16 + l15;
                const int c = nt * 2 + (qd >> 1);
                bv[dt] = *reinterpret_cast<const s4v*>(
                    V_ + r * 128 + ((c ^ l15) & 15) * 8 + (qd & 1) * 4);
            }

            #pragma unroll
            for (int g = 0; g < 2; ++g) {
                f4v zz = (f4v){0.f, 0.f, 0.f, 0.f};
                zz = __builtin_amdgcn_mfma_f32_16x16x32_bf16(ak0, bq[g][0], zz, 0, 0, 0);
                zz = __builtin_amdgcn_mfma_f32_16x16x32_bf16(ak1, bq[g][1], zz, 0, 0, 0);
                const float p0 = __builtin_amdgcn_exp2f(zz[0]);
                const float p1 = __builtin_amdgcn_exp2f(zz[1]);
                const float p2 = __builtin_amdgcn_exp2f(zz[2]);
                const float p3 = __builtin_amdgcn_exp2f(zz[3]);
                const s4v pf = pack_p(p0, p1, p2, p3);
                #pragma unroll
                for (int dt = 0; dt < 4; ++dt)
                    oacc[g][dt] = __builtin_amdgcn_mfma_f32_16x16x16bf16_1k(
                        pf, bv[dt], oacc[g][dt], 0, 0, 0);
                lones[g] = __builtin_amdgcn_mfma_f32_16x16x16bf16_1k(
                    pf, vone, lones[g], 0, 0, 0);
            }
        }
    }

    #pragma unroll
    for (int g = 0; g < 2; ++g) {
        #pragma unroll
        for (int r = 0; r < 4; ++r) {
            const float inv = 1.0f / lones[g][r];
            const int s = q0 + w * 32 + g * 16 + qd * 4 + r;
            unsigned short* __restrict__ dst =
                Cb + ((size_t)(b * S_ + s)) * HID_ + h * HD_ + l15;
            #pragma unroll
            for (int dt = 0; dt < 4; ++dt)
                dst[dt * 16] = f2b_rne(oacc[g][dt][r] * inv);
        }
    }
}

// ---------------------------------------------------------------------------
extern "C" void kernel_launch(void* const* d_in, const int* in_sizes, int n_in,
                              void* d_out, int out_size, void* d_ws, size_t ws_size,
                              hipStream_t stream)
{
    const float* X  = (const float*)d_in[0];
    const float* Wq = (const float*)d_in[1];
    const float* bq = (const float*)d_in[2];
    const float* Wk = (const float*)d_in[3];
    const float* bk = (const float*)d_in[4];
    const float* Wv = (const float*)d_in[5];
    const float* bv = (const float*)d_in[6];
    const float* Wo = (const float*)d_in[7];
    const float* bo = (const float*)d_in[8];
    float* out = (float*)d_out;

    // ws (ushort elems): Wot 1M | Xb 4M | Wqt 1M | Wkt 1M | Wvt 1M |
    //                    Qb 4M | Kb 4M | Vt 4M | Cb 4M = 48 MB
    // Wqt..Wvt contiguous = concatenated [3072][1024] B-matrix for fused QKV.
    const size_t QKV = (size_t)B_ * NH_ * S_ * HD_;   // 4,194,304
    const size_t WSZ = (size_t)HID_ * HID_;           // 1,048,576
    unsigned short* Wot = (unsigned short*)d_ws;
    unsigned short* Xb  = Wot + WSZ;
    unsigned short* Wqt = Xb  + QKV;
    unsigned short* Wkt = Wqt + WSZ;
    unsigned short* Wvt = Wkt + WSZ;
    unsigned short* Qb  = Wvt + WSZ;
    unsigned short* Kb  = Qb + QKV;
    unsigned short* Vt  = Kb + QKV;
    unsigned short* Cb  = Vt + QKV;

    prep_kernel<<<dim3(16, 16, 8), 256, 0, stream>>>(
        X, Wq, Wk, Wv, Wo, Xb, Wqt, Wkt, Wvt, Wot);
    gemm_qkv_kernel<<<dim3(24, 32), 256, 0, stream>>>(
        Xb, Wqt, bq, bk, bv, Qb, Kb, Vt);
    attn_kernel<<<dim3(S_ / 128, B_ * NH_), 256, 0, stream>>>(
        (const bf16*)Qb, (const bf16*)Kb, (const bf16*)Vt, Cb);
    gemm_out_kernel<<<dim3(8, 32), 256, 0, stream>>>(Cb, Wot, bo, out);
}